// Round 8
// baseline (220.247 us; speedup 1.0000x reference)
//
#include <hip/hip_runtime.h>
#include <hip/hip_bf16.h>

typedef __hip_bfloat16 bf16;
typedef _Float16 h16;
typedef __attribute__((ext_vector_type(8))) _Float16 h16x8;
typedef __attribute__((ext_vector_type(4))) float f32x4;
typedef __attribute__((ext_vector_type(16))) float f32x16;

__device__ __forceinline__ float lrelu(float x) { return fmaxf(x, 0.1f * x); }
__device__ __forceinline__ float ldE(const void* p, long i, int f32) {
    return f32 ? ((const float*)p)[i] : __bfloat162float(((const bf16*)p)[i]);
}
__device__ __forceinline__ uint2 pack4(float a, float b, float c, float d) {
    union { _Float16 h[4]; uint2 u; } t;
    t.h[0] = (_Float16)a; t.h[1] = (_Float16)b; t.h[2] = (_Float16)c; t.h[3] = (_Float16)d;
    return t.u;
}
__device__ __forceinline__ unsigned umx(unsigned a, unsigned b) { return a > b ? a : b; }
#define LDS_FENCE() asm volatile("s_waitcnt lgkmcnt(0)" ::: "memory")

// ---------------- workspace layout ----------------
// float region (wsf):
//   [64..79] fb1 [80..95] fb2 [96..127] fb3 [128..159] fb4
//   [160..223] fbd [224..287] qwo [288] fbo
//   int flag @ 290;  scales @ 296..301 (w1,w2,w3,w4,wd,wo — already /127)
// f16 frag region wh = (h16*)(wsf+292... after 302 floats actually) —
//   keep legacy base wsf+292 but scales live at 296..301 inside the gap
//   before wh? NO: wh base moved to wsf+304 to avoid overlap.
//   F2 @0 (1024), F3 @1024 (2560), F4 @3584 (5120), FD @8704 (55296),
//   F1 @64000 (512)

__device__ __forceinline__ float qv(const void* src, int idx, float sc, int f32) {
    float w = ldE(src, idx, f32);
    float q = rintf(w / sc);                    // round-half-even like jnp.round
    return fminf(127.f, fmaxf(-127.f, q)) * sc; // clip then dequant
}

// Vectorized per-tensor scale (safe for repeated calls in one block).
__device__ float block_scale(const void* src, int n, int f32, int tid, float* red) {
    unsigned m = 0;
    const uint4* p = (const uint4*)src;
    if (f32) {
        int nv = n >> 2;
        for (int i = tid; i < nv; i += 256) {
            uint4 u = p[i];
            m = umx(m, u.x & 0x7FFFFFFFu); m = umx(m, u.y & 0x7FFFFFFFu);
            m = umx(m, u.z & 0x7FFFFFFFu); m = umx(m, u.w & 0x7FFFFFFFu);
        }
        union { unsigned u; float f; } c; c.u = m;
        red[tid] = c.f;
    } else {
        int nv = n >> 3;
        for (int i = tid; i < nv; i += 256) {
            uint4 u = p[i];
            unsigned a;
            a = u.x & 0x7FFF7FFFu; m = umx(m, a >> 16); m = umx(m, a & 0xFFFFu);
            a = u.y & 0x7FFF7FFFu; m = umx(m, a >> 16); m = umx(m, a & 0xFFFFu);
            a = u.z & 0x7FFF7FFFu; m = umx(m, a >> 16); m = umx(m, a & 0xFFFFu);
            a = u.w & 0x7FFF7FFFu; m = umx(m, a >> 16); m = umx(m, a & 0xFFFFu);
        }
        union { unsigned u; float f; } c; c.u = m << 16;
        red[tid] = c.f;
    }
    __syncthreads();
    for (int s = 128; s > 0; s >>= 1) {
        if (tid < s) red[tid] = fmaxf(red[tid], red[tid + s]);
        __syncthreads();
    }
    float r = red[0] / 127.f;   // exact division, matches np max|w|/127
    __syncthreads();            // allow red reuse by the next call
    return r;
}

// 1 block: dtype flag, all 6 scales, biases, qwo.
__global__ void __launch_bounds__(256) prep_scales(
    const unsigned short* __restrict__ xu,
    const void* __restrict__ w1, const void* __restrict__ w2,
    const void* __restrict__ w3, const void* __restrict__ w4,
    const void* __restrict__ wd, const void* __restrict__ wo,
    const void* __restrict__ b1, const void* __restrict__ b2,
    const void* __restrict__ b3, const void* __restrict__ b4,
    const void* __restrict__ bd, const void* __restrict__ bo,
    float* __restrict__ wsf)
{
    int tid = threadIdx.x;
    __shared__ float red[256];
    __shared__ int cnt;
    if (tid == 0) cnt = 0;
    __syncthreads();
    int bad = 0;
    for (int i = tid; i < 2048; i += 256) {
        int e = (xu[i] >> 7) & 0xFF;      // bf16 exponent of x's halfwords
        if (e >= 147) bad = 1;            // |v| >= 2^20: x is not bf16 data
    }
    atomicAdd(&cnt, bad);
    __syncthreads();
    const int f32 = (cnt > 4) ? 1 : 0;

    float s1 = block_scale(w1, 64, f32, tid, red);
    float s2 = block_scale(w2, 768, f32, tid, red);
    float s3 = block_scale(w3, 2560, f32, tid, red);
    float s4 = block_scale(w4, 5120, f32, tid, red);
    float sd = block_scale(wd, 55296, f32, tid, red);
    float so = block_scale(wo, 64, f32, tid, red);

    if (tid < 64) wsf[224 + tid] = qv(wo, tid, so, f32);
    if (tid < 16)        wsf[64 + tid]        = ldE(b1, tid, f32);
    else if (tid < 32)   wsf[80 + tid - 16]   = ldE(b2, tid - 16, f32);
    else if (tid < 64)   wsf[96 + tid - 32]   = ldE(b3, tid - 32, f32);
    else if (tid < 96)   wsf[128 + tid - 64]  = ldE(b4, tid - 64, f32);
    else if (tid < 160)  wsf[160 + tid - 96]  = ldE(bd, tid - 96, f32);
    else if (tid == 160) wsf[288]             = ldE(bo, 0, f32);
    if (tid == 0) {
        ((int*)wsf)[290] = f32;
        wsf[296] = s1; wsf[297] = s2; wsf[298] = s3;
        wsf[299] = s4; wsf[300] = sd; wsf[301] = so;
    }
}

// grid = 56: 0..47 FD slices, 48 F1, 49 F2, 50..51 F3, 52..55 F4.
__global__ void __launch_bounds__(256) prep_shuffle(
    const void* __restrict__ w1, const void* __restrict__ w2,
    const void* __restrict__ w3, const void* __restrict__ w4,
    const void* __restrict__ wd,
    float* __restrict__ wsf)
{
    int tid = threadIdx.x, which = blockIdx.x;
    const int f32 = ((const int*)wsf)[290];
    h16* wh = (h16*)(wsf + 304);

    if (which < 48) {                     // dense frag slice (1152 elems)
        float sc = wsf[300];
        int e1 = (which + 1) * 1152;
        for (int e = which * 1152 + tid; e < e1; e += 256) {
            int j = e & 7, l = (e >> 3) & 63, t = e >> 9;   // t = mt*27 + c
            int mt = t / 27, c = t - mt * 27;
            int o = mt * 16 + (l & 15);
            int k = c * 32 + ((l >> 4) & 3) * 8 + j;
            int i = k >> 5, cch = k & 31;
            wh[8704 + e] = (h16)qv(wd, o * 864 + cch * 27 + i, sc, f32);
        }
    } else if (which == 48) {             // conv1 A-frags: k = dk*8+ci, real dk<2,ci<2
        float sc = wsf[296];
        for (int e = tid; e < 512; e += 256) {
            int l = e >> 3, j = e & 7;
            int co = l & 15, kg = (l >> 4) & 3;
            float v = (kg < 2 && j < 2) ? qv(w1, co * 4 + j * 2 + kg, sc, f32) : 0.f;
            wh[64000 + e] = (h16)v;
        }
    } else if (which == 49) {             // conv2 A-frags: k = dk*16+ci, pad dk=3
        float sc = wsf[297];
        for (int e = tid; e < 1024; e += 256) {
            int c = e >> 9, l = (e >> 3) & 63, j = e & 7;
            int mm = l & 15;
            int k = c * 32 + ((l >> 4) & 3) * 8 + j;
            int dk = k >> 4, ci = k & 15;
            float v = (dk < 3) ? qv(w2, (mm * 16 + ci) * 3 + dk, sc, f32) : 0.f;
            wh[0 + e] = (h16)v;
        }
    } else if (which < 52) {              // conv3 A-frags: k = dk*16+ci, dk = chunk
        float sc = wsf[298];
        int e0 = (which - 50) * 1280;
        for (int e = e0 + tid; e < e0 + 1280; e += 256) {
            int c = e >> 9, l = (e >> 3) & 63, j = e & 7;
            int mm = l & 31;
            int ci = ((l >> 5) & 1) * 8 + j;
            wh[1024 + e] = (h16)qv(w3, (mm * 16 + ci) * 5 + c, sc, f32);
        }
    } else {                              // conv4 A-frags: k = dk*32+ci
        float sc = wsf[299];
        int e0 = (which - 52) * 1280;
        for (int e = e0 + tid; e < e0 + 1280; e += 256) {
            int c = e >> 9, l = (e >> 3) & 63, j = e & 7;
            int mm = l & 31;
            int k = c * 16 + ((l >> 5) & 1) * 8 + j;
            int dk = k >> 5, ci = k & 31;
            wh[3584 + e] = (h16)qv(w4, (mm * 32 + ci) * 5 + dk, sc, f32);
        }
    }
}

// MFMA convs with chunked [k-group][pos][8 h16] LDS layouts. Max-pools are
// fused into conv2/conv4 epilogues via __shfl_xor(v,1): pool pairs are
// adjacent lanes in the MFMA C-layout, so no pool stage, no act2/act4
// materialization, 2 fewer fences. Wave-private U/V make the in-place
// pooled writes safe (write rows of tile t always < read rows of tiles >t).
__global__ void __launch_bounds__(256, 2) qcnn_main(
    const void* __restrict__ x,      // [B][2][128] bf16 or f32
    const float* __restrict__ wsf,
    void* __restrict__ out)          // [B]
{
    const int f32flag = ((const int*)wsf)[290];
    const h16*  wh  = (const h16*)(wsf + 304);
    const h16*  F2g = wh;
    const h16*  F3g = wh + 1024;
    const h16*  F4g = wh + 3584;
    const h16*  FDg = wh + 8704;
    const h16*  F1g = wh + 64000;

    __shared__ __align__(16) h16 Uall[4][2112];   // act1 (2g x 132 rows) / pooled
    __shared__ __align__(16) h16 Vall[4][2208];   // xi8 staging / act3 (4g x 69)
    __shared__ __align__(16) h16 flatb[8][872];
    __shared__ float red[256];

    int tid  = threadIdx.x;
    int lane = tid & 63;
    int w    = __builtin_amdgcn_readfirstlane(tid >> 6);
    int n16  = lane & 15, kg16 = (lane >> 4) & 3;
    int n32  = lane & 31, kg32 = (lane >> 5) & 1;
    int o16  = kg16 * 4;
    h16* U = Uall[w];
    h16* V = Vall[w];
    long b0 = (long)blockIdx.x * 8;

    // loop-invariant A fragments (16B/lane coalesced)
    h16x8 a1, a2[2], a3[5], a4[10];
    a1 = *(const h16x8*)&F1g[lane * 8];
#pragma unroll
    for (int c = 0; c < 2; ++c)  a2[c] = *(const h16x8*)&F2g[c * 512 + lane * 8];
#pragma unroll
    for (int c = 0; c < 5; ++c)  a3[c] = *(const h16x8*)&F3g[c * 512 + lane * 8];
#pragma unroll
    for (int c = 0; c < 10; ++c) a4[c] = *(const h16x8*)&F4g[c * 512 + lane * 8];
    f32x4 b1v = *(const f32x4*)&wsf[64 + o16];   // conv1 C-init
    f32x4 b2v = *(const f32x4*)&wsf[80 + o16];   // conv2 C-init

    const h16 hz = (h16)0.f;
    const h16x8 zrow = {hz, hz, hz, hz, hz, hz, hz, hz};

    for (int it = 0; it < 2; ++it) {
        int slot = w * 2 + it;
        long sb = (b0 + slot) * 256;

        // ---- stage x as xi8 rows in V: row p = {x0[p], x1[p], 0...} ----
        LDS_FENCE();   // prev iteration's V readers (conv4) done
        {
            float x00 = ldE(x, sb + lane, f32flag);
            float x10 = ldE(x, sb + 128 + lane, f32flag);
            float x01 = ldE(x, sb + 64 + lane, f32flag);
            float x11 = ldE(x, sb + 192 + lane, f32flag);
            h16x8 r0 = zrow, r1 = zrow;
            r0[0] = (h16)x00; r0[1] = (h16)x10;
            r1[0] = (h16)x01; r1[1] = (h16)x11;
            *(h16x8*)&V[lane * 8]        = r0;
            *(h16x8*)&V[(64 + lane) * 8] = r1;
            if (lane < 3) *(h16x8*)&V[(128 + lane) * 8] = zrow;  // pad rows
        }
        LDS_FENCE();

        // ---- conv1 (16x16x32, K pad 4->32): xi8 -> act1 U[2g][127] ----
#pragma unroll
        for (int t = 0; t < 8; ++t) {
            int n = t * 16 + n16;
            f32x4 acc = b1v;
            h16x8 bfr = *(const h16x8*)&V[(n + kg16) * 8];
            acc = __builtin_amdgcn_mfma_f32_16x16x32_f16(a1, bfr, acc, 0, 0, 0);
            if (n < 127) {
                uint2 p = pack4(lrelu(acc[0]), lrelu(acc[1]), lrelu(acc[2]), lrelu(acc[3]));
                *(uint2*)&U[(o16 >> 3) * 1056 + n * 8 + (o16 & 7)] = p;
            }
        }
        if (lane < 8) {   // zero act1 pad rows 127..130 (both groups)
            int g = lane & 1, row = 127 + (lane >> 1);
            *(uint4*)&U[g * 1056 + row * 8] = make_uint4(0, 0, 0, 0);
        }
        LDS_FENCE();

        // ---- conv2 (16x16x32) + fused pool1: act1 -> pooled U[2g][62] ----
#pragma unroll
        for (int t = 0; t < 8; ++t) {
            int n = t * 16 + n16;
            f32x4 acc = b2v;
#pragma unroll
            for (int c = 0; c < 2; ++c) {
                int k0 = c * 32 + kg16 * 8;
                int dk = k0 >> 4, g = (k0 & 15) >> 3;
                h16x8 bfr = *(const h16x8*)&U[g * 1056 + (n + dk) * 8];
                acc = __builtin_amdgcn_mfma_f32_16x16x32_f16(a2[c], bfr, acc, 0, 0, 0);
            }
            float v0 = lrelu(acc[0]), v1 = lrelu(acc[1]);
            float v2 = lrelu(acc[2]), v3 = lrelu(acc[3]);
            v0 = fmaxf(v0, __shfl_xor(v0, 1, 64));
            v1 = fmaxf(v1, __shfl_xor(v1, 1, 64));
            v2 = fmaxf(v2, __shfl_xor(v2, 1, 64));
            v3 = fmaxf(v3, __shfl_xor(v3, 1, 64));
            if (!(n16 & 1)) {
                int p = t * 8 + (n16 >> 1);
                if (p < 62)
                    *(uint2*)&U[(o16 >> 3) * 1056 + p * 8 + (o16 & 7)] = pack4(v0, v1, v2, v3);
            }
        }
        LDS_FENCE();

        // ---- conv3 (32x32x16): pooled -> act3 V[4g][58] ----
#pragma unroll
        for (int t = 0; t < 2; ++t) {
            int n = t * 32 + n32;
            f32x16 acc = {0.f,0.f,0.f,0.f,0.f,0.f,0.f,0.f,0.f,0.f,0.f,0.f,0.f,0.f,0.f,0.f};
#pragma unroll
            for (int c = 0; c < 5; ++c) {
                h16x8 bfr = *(const h16x8*)&U[kg32 * 1056 + (n + c) * 8];
                acc = __builtin_amdgcn_mfma_f32_32x32x16_f16(a3[c], bfr, acc, 0, 0, 0);
            }
            if (n < 58) {
#pragma unroll
                for (int g = 0; g < 4; ++g) {
                    int r0 = 8 * g + 4 * kg32;
                    f32x4 bv = *(const f32x4*)&wsf[96 + r0];
                    uint2 p = pack4(lrelu(acc[4*g+0] + bv[0]), lrelu(acc[4*g+1] + bv[1]),
                                    lrelu(acc[4*g+2] + bv[2]), lrelu(acc[4*g+3] + bv[3]));
                    *(uint2*)&V[g * 552 + n * 8 + 4 * kg32] = p;
                }
            }
        }
        LDS_FENCE();

        // ---- conv4 (32x32x16) + fused pool2: act3 -> flatb[slot] ----
#pragma unroll
        for (int t = 0; t < 2; ++t) {
            int n32_ = n32;  (void)n32_;
            f32x16 acc = {0.f,0.f,0.f,0.f,0.f,0.f,0.f,0.f,0.f,0.f,0.f,0.f,0.f,0.f,0.f,0.f};
#pragma unroll
            for (int c = 0; c < 10; ++c) {
                int k0 = c * 16 + kg32 * 8;
                int dk = k0 >> 5, g = (k0 >> 3) & 3;
                h16x8 bfr = *(const h16x8*)&V[g * 552 + (t * 32 + n32 + dk) * 8];
                acc = __builtin_amdgcn_mfma_f32_32x32x16_f16(a4[c], bfr, acc, 0, 0, 0);
            }
#pragma unroll
            for (int g = 0; g < 4; ++g) {
                f32x4 bv = *(const f32x4*)&wsf[128 + 8 * g + 4 * kg32];
                float m0 = lrelu(acc[4*g+0] + bv[0]);
                float m1 = lrelu(acc[4*g+1] + bv[1]);
                float m2 = lrelu(acc[4*g+2] + bv[2]);
                float m3 = lrelu(acc[4*g+3] + bv[3]);
                m0 = fmaxf(m0, __shfl_xor(m0, 1, 64));
                m1 = fmaxf(m1, __shfl_xor(m1, 1, 64));
                m2 = fmaxf(m2, __shfl_xor(m2, 1, 64));
                m3 = fmaxf(m3, __shfl_xor(m3, 1, 64));
                if (!(n32 & 1)) {
                    int fp = t * 16 + (n32 >> 1);
                    if (fp < 27)
                        *(uint2*)&flatb[slot][(g * 27 + fp) * 8 + 4 * kg32] = pack4(m0, m1, m2, m3);
                }
            }
        }
    }
    __syncthreads();

    // ---- dense (16x16x32): flatb[8][864] @ FD, wave w = m-tile ----
    int o0g = w * 16 + o16;
    f32x4 dacc = *(const f32x4*)&wsf[160 + o0g];  // bias in C
    for (int c = 0; c < 27; ++c) {
        h16x8 aw = *(const h16x8*)&FDg[((w * 27 + c) * 64 + lane) * 8];
        h16x8 bh = *(const h16x8*)&flatb[lane & 7][(kg16 * 27 + c) * 8];
        dacc = __builtin_amdgcn_mfma_f32_16x16x32_f16(aw, bh, dacc, 0, 0, 0);
    }
    f32x4 qov = *(const f32x4*)&wsf[224 + o0g];
    float part = 0.f;
#pragma unroll
    for (int q = 0; q < 4; ++q) part += lrelu(dacc[q]) * qov[q];
    red[tid] = part;
    __syncthreads();
    if (tid < 8) {
        float y = wsf[288];
#pragma unroll
        for (int g = 0; g < 16; ++g) y += red[(g >> 2) * 64 + (g & 3) * 16 + tid];
        if (f32flag) ((float*)out)[b0 + tid] = y;
        else         ((bf16*)out)[b0 + tid] = __float2bfloat16(y);
    }
}

extern "C" void kernel_launch(void* const* d_in, const int* in_sizes, int n_in,
                              void* d_out, int out_size, void* d_ws, size_t ws_size,
                              hipStream_t stream) {
    const void* x  = d_in[0];
    const void* w1 = d_in[1];
    const void* b1 = d_in[2];
    const void* w2 = d_in[3];
    const void* b2 = d_in[4];
    const void* w3 = d_in[5];
    const void* b3 = d_in[6];
    const void* w4 = d_in[7];
    const void* b4 = d_in[8];
    const void* wd = d_in[9];
    const void* bd = d_in[10];
    const void* wo = d_in[11];
    const void* bo = d_in[12];
    float* wsf = (float*)d_ws;

    int B = in_sizes[0] / 256;            // 32768
    prep_scales<<<1, 256, 0, stream>>>((const unsigned short*)x,
                                       w1, w2, w3, w4, wd, wo,
                                       b1, b2, b3, b4, bd, bo, wsf);
    prep_shuffle<<<56, 256, 0, stream>>>(w1, w2, w3, w4, wd, wsf);
    qcnn_main<<<B / 8, 256, 0, stream>>>(x, wsf, d_out);
}

// Round 9
// 195.230 us; speedup vs baseline: 1.1281x; 1.1281x over previous
//
#include <hip/hip_runtime.h>
#include <hip/hip_bf16.h>

typedef __hip_bfloat16 bf16;
typedef _Float16 h16;
typedef __attribute__((ext_vector_type(8))) _Float16 h16x8;
typedef __attribute__((ext_vector_type(4))) float f32x4;
typedef __attribute__((ext_vector_type(16))) float f32x16;

__device__ __forceinline__ float lrelu(float x) { return fmaxf(x, 0.1f * x); }
__device__ __forceinline__ float ldE(const void* p, long i, int f32) {
    return f32 ? ((const float*)p)[i] : __bfloat162float(((const bf16*)p)[i]);
}
__device__ __forceinline__ uint2 pack4(float a, float b, float c, float d) {
    union { _Float16 h[4]; uint2 u; } t;
    t.h[0] = (_Float16)a; t.h[1] = (_Float16)b; t.h[2] = (_Float16)c; t.h[3] = (_Float16)d;
    return t.u;
}
__device__ __forceinline__ unsigned umx(unsigned a, unsigned b) { return a > b ? a : b; }
// Compiler-only ordering barrier. HW guarantee: a wave's LDS (DS) operations
// complete IN ORDER (lgkmcnt in-order for DS; only SMEM is out-of-order), and
// all U/V buffers are wave-private -> same-wave program order suffices for
// memory RAW/WAR. No s_waitcnt drain needed; compiler still inserts lgkmcnt
// waits for register deps of ds_read results.
#define LDS_FENCE() asm volatile("" ::: "memory")

// ---------------- workspace layout ----------------
// float region (wsf):
//   [64..79] fb1 [80..95] fb2 [96..127] fb3 [128..159] fb4
//   [160..223] fbd [224..287] qwo [288] fbo   int flag @ index 290
// f16 frag region wh = (h16*)(wsf+292):
//   F2 @0 (1024), F3 @1024 (2560), F4 @3584 (5120), FD @8704 (55296),
//   F1 @64000 (512)   (conv1 16x16x32 frags, k = dk*8+ci, K pad 4->32)

__device__ __forceinline__ float qv(const void* src, int idx, float sc, int f32) {
    float w = ldE(src, idx, f32);
    float q = rintf(w / sc);                    // round-half-even like jnp.round
    return fminf(127.f, fmaxf(-127.f, q)) * sc; // clip then dequant
}

// Vectorized per-tensor scale: uint4 loads + integer abs-max (bit patterns of
// finite IEEE floats are magnitude-monotone after stripping sign).
__device__ float block_scale(const void* src, int n, int f32, int tid, float* red) {
    unsigned m = 0;
    const uint4* p = (const uint4*)src;
    if (f32) {
        int nv = n >> 2;
        for (int i = tid; i < nv; i += 256) {
            uint4 u = p[i];
            m = umx(m, u.x & 0x7FFFFFFFu); m = umx(m, u.y & 0x7FFFFFFFu);
            m = umx(m, u.z & 0x7FFFFFFFu); m = umx(m, u.w & 0x7FFFFFFFu);
        }
        union { unsigned u; float f; } c; c.u = m;
        red[tid] = c.f;
    } else {
        int nv = n >> 3;
        for (int i = tid; i < nv; i += 256) {
            uint4 u = p[i];
            unsigned a;
            a = u.x & 0x7FFF7FFFu; m = umx(m, a >> 16); m = umx(m, a & 0xFFFFu);
            a = u.y & 0x7FFF7FFFu; m = umx(m, a >> 16); m = umx(m, a & 0xFFFFu);
            a = u.z & 0x7FFF7FFFu; m = umx(m, a >> 16); m = umx(m, a & 0xFFFFu);
            a = u.w & 0x7FFF7FFFu; m = umx(m, a >> 16); m = umx(m, a & 0xFFFFu);
        }
        union { unsigned u; float f; } c; c.u = m << 16;
        red[tid] = c.f;
    }
    __syncthreads();
    for (int s = 128; s > 0; s >>= 1) {
        if (tid < s) red[tid] = fmaxf(red[tid], red[tid + s]);
        __syncthreads();
    }
    return red[0] / 127.f;   // exact division, matches np max|w|/127
}

// grid = 57: 0..47 FD slices, 48 F1, 49 F2, 50..51 F3, 52..55 F4,
// 56 qwo + biases + dtype flag.
__global__ void __launch_bounds__(256) prep(
    const unsigned short* __restrict__ xu,
    const void* __restrict__ w1, const void* __restrict__ w2,
    const void* __restrict__ w3, const void* __restrict__ w4,
    const void* __restrict__ wd, const void* __restrict__ wo,
    const void* __restrict__ b1, const void* __restrict__ b2,
    const void* __restrict__ b3, const void* __restrict__ b4,
    const void* __restrict__ bd, const void* __restrict__ bo,
    float* __restrict__ wsf)
{
    int tid = threadIdx.x, which = blockIdx.x;
    __shared__ float red[256];
    __shared__ int cnt;
    if (tid == 0) cnt = 0;
    __syncthreads();
    int bad = 0;
    for (int i = tid; i < 2048; i += 256) {
        int e = (xu[i] >> 7) & 0xFF;      // bf16 exponent of x's halfwords
        if (e >= 147) bad = 1;            // |v| >= 2^20: x is not bf16 data
    }
    atomicAdd(&cnt, bad);
    __syncthreads();
    const int f32 = (cnt > 4) ? 1 : 0;
    h16* wh = (h16*)(wsf + 292);

    if (which < 48) {                     // dense frag slice (1152 elems)
        float sc = block_scale(wd, 55296, f32, tid, red);
        int e1 = (which + 1) * 1152;
        for (int e = which * 1152 + tid; e < e1; e += 256) {
            int j = e & 7, l = (e >> 3) & 63, t = e >> 9;   // t = mt*27 + c
            int mt = t / 27, c = t - mt * 27;
            int o = mt * 16 + (l & 15);
            int k = c * 32 + ((l >> 4) & 3) * 8 + j;
            int i = k >> 5, cch = k & 31;
            wh[8704 + e] = (h16)qv(wd, o * 864 + cch * 27 + i, sc, f32);
        }
    } else if (which == 48) {             // conv1 A-frags: k = dk*8+ci, real dk<2,ci<2
        float sc = block_scale(w1, 64, f32, tid, red);
        for (int e = tid; e < 512; e += 256) {
            int l = e >> 3, j = e & 7;
            int co = l & 15, kg = (l >> 4) & 3;
            float v = (kg < 2 && j < 2) ? qv(w1, co * 4 + j * 2 + kg, sc, f32) : 0.f;
            wh[64000 + e] = (h16)v;
        }
    } else if (which == 49) {             // conv2 A-frags: k = dk*16+ci, pad dk=3
        float sc = block_scale(w2, 768, f32, tid, red);
        for (int e = tid; e < 1024; e += 256) {
            int c = e >> 9, l = (e >> 3) & 63, j = e & 7;
            int mm = l & 15;
            int k = c * 32 + ((l >> 4) & 3) * 8 + j;
            int dk = k >> 4, ci = k & 15;
            float v = (dk < 3) ? qv(w2, (mm * 16 + ci) * 3 + dk, sc, f32) : 0.f;
            wh[0 + e] = (h16)v;
        }
    } else if (which < 52) {              // conv3 A-frags: k = dk*16+ci, dk = chunk
        float sc = block_scale(w3, 2560, f32, tid, red);
        int e0 = (which - 50) * 1280;
        for (int e = e0 + tid; e < e0 + 1280; e += 256) {
            int c = e >> 9, l = (e >> 3) & 63, j = e & 7;
            int mm = l & 31;
            int ci = ((l >> 5) & 1) * 8 + j;
            wh[1024 + e] = (h16)qv(w3, (mm * 16 + ci) * 5 + c, sc, f32);
        }
    } else if (which < 56) {              // conv4 A-frags: k = dk*32+ci
        float sc = block_scale(w4, 5120, f32, tid, red);
        int e0 = (which - 52) * 1280;
        for (int e = e0 + tid; e < e0 + 1280; e += 256) {
            int c = e >> 9, l = (e >> 3) & 63, j = e & 7;
            int mm = l & 31;
            int k = c * 16 + ((l >> 5) & 1) * 8 + j;
            int dk = k >> 5, ci = k & 31;
            wh[3584 + e] = (h16)qv(w4, (mm * 32 + ci) * 5 + dk, sc, f32);
        }
    } else {                              // qwo + biases + flag
        float sc = block_scale(wo, 64, f32, tid, red);
        if (tid < 64) wsf[224 + tid] = qv(wo, tid, sc, f32);
        if (tid < 16)        wsf[64 + tid]        = ldE(b1, tid, f32);
        else if (tid < 32)   wsf[80 + tid - 16]   = ldE(b2, tid - 16, f32);
        else if (tid < 64)   wsf[96 + tid - 32]   = ldE(b3, tid - 32, f32);
        else if (tid < 96)   wsf[128 + tid - 64]  = ldE(b4, tid - 64, f32);
        else if (tid < 160)  wsf[160 + tid - 96]  = ldE(bd, tid - 96, f32);
        else if (tid == 160) wsf[288]             = ldE(bo, 0, f32);
        if (tid == 0) ((int*)wsf)[290] = f32;
    }
}

// All convs on MFMA with chunked [k-group][pos][8 h16] LDS layouts: every
// B-fragment read is one lane-contiguous 16B ds_read_b128 (no conflicts).
// Stage boundaries are compiler-only barriers (see LDS_FENCE comment): the
// wave-private buffers + in-order DS pipe make s_waitcnt drains unnecessary.
__global__ void __launch_bounds__(256, 2) qcnn_main(
    const void* __restrict__ x,      // [B][2][128] bf16 or f32
    const float* __restrict__ wsf,
    void* __restrict__ out)          // [B]
{
    const int f32flag = ((const int*)wsf)[290];
    const h16*  wh  = (const h16*)(wsf + 292);
    const h16*  F2g = wh;
    const h16*  F3g = wh + 1024;
    const h16*  F4g = wh + 3584;
    const h16*  FDg = wh + 8704;
    const h16*  F1g = wh + 64000;

    __shared__ __align__(16) h16 Uall[4][2112];
    __shared__ __align__(16) h16 Vall[4][2208];
    __shared__ __align__(16) h16 flatb[8][872];
    __shared__ float red[256];

    int tid  = threadIdx.x;
    int lane = tid & 63;
    int w    = __builtin_amdgcn_readfirstlane(tid >> 6);
    int n16  = lane & 15, kg16 = (lane >> 4) & 3;
    int n32  = lane & 31, kg32 = (lane >> 5) & 1;
    int o16  = kg16 * 4;
    h16* U = Uall[w];
    h16* V = Vall[w];
    long b0 = (long)blockIdx.x * 8;

    // loop-invariant A fragments (16B/lane coalesced)
    h16x8 a1, a2[2], a3[5], a4[10];
    a1 = *(const h16x8*)&F1g[lane * 8];
#pragma unroll
    for (int c = 0; c < 2; ++c)  a2[c] = *(const h16x8*)&F2g[c * 512 + lane * 8];
#pragma unroll
    for (int c = 0; c < 5; ++c)  a3[c] = *(const h16x8*)&F3g[c * 512 + lane * 8];
#pragma unroll
    for (int c = 0; c < 10; ++c) a4[c] = *(const h16x8*)&F4g[c * 512 + lane * 8];
    f32x4 b1v = *(const f32x4*)&wsf[64 + o16];   // conv1 C-init
    f32x4 b2v = *(const f32x4*)&wsf[80 + o16];   // conv2 C-init

    const h16 hz = (h16)0.f;
    const h16x8 zrow = {hz, hz, hz, hz, hz, hz, hz, hz};

    for (int it = 0; it < 2; ++it) {
        int slot = w * 2 + it;
        long sb = (b0 + slot) * 256;

        // ---- stage x as xi8 rows in V: row p = {x0[p], x1[p], 0...} ----
        LDS_FENCE();   // order after prev iteration's V readers (conv4)
        {
            float x00 = ldE(x, sb + lane, f32flag);
            float x10 = ldE(x, sb + 128 + lane, f32flag);
            float x01 = ldE(x, sb + 64 + lane, f32flag);
            float x11 = ldE(x, sb + 192 + lane, f32flag);
            h16x8 r0 = zrow, r1 = zrow;
            r0[0] = (h16)x00; r0[1] = (h16)x10;
            r1[0] = (h16)x01; r1[1] = (h16)x11;
            *(h16x8*)&V[lane * 8]        = r0;
            *(h16x8*)&V[(64 + lane) * 8] = r1;
            if (lane < 3) *(h16x8*)&V[(128 + lane) * 8] = zrow;  // pad rows
        }
        LDS_FENCE();

        // ---- conv1 (16x16x32, K pad 4->32): xi8 -> act1 U[2g][127] ----
#pragma unroll
        for (int t = 0; t < 8; ++t) {
            int n = t * 16 + n16;
            f32x4 acc = b1v;
            h16x8 bfr = *(const h16x8*)&V[(n + kg16) * 8];
            acc = __builtin_amdgcn_mfma_f32_16x16x32_f16(a1, bfr, acc, 0, 0, 0);
            if (n < 127) {
                uint2 p = pack4(lrelu(acc[0]), lrelu(acc[1]), lrelu(acc[2]), lrelu(acc[3]));
                *(uint2*)&U[(o16 >> 3) * 1056 + n * 8 + (o16 & 7)] = p;
            }
        }
        if (lane < 8) {   // zero act1 pad rows 127..130 (both groups)
            int g = lane & 1, row = 127 + (lane >> 1);
            *(uint4*)&U[g * 1056 + row * 8] = make_uint4(0, 0, 0, 0);
        }
        LDS_FENCE();

        // ---- conv2 (16x16x32): act1 -> act2 V[2g][125] ----
#pragma unroll
        for (int t = 0; t < 8; ++t) {
            int n = t * 16 + n16;
            f32x4 acc = b2v;
#pragma unroll
            for (int c = 0; c < 2; ++c) {
                int k0 = c * 32 + kg16 * 8;
                int dk = k0 >> 4, g = (k0 & 15) >> 3;
                h16x8 bfr = *(const h16x8*)&U[g * 1056 + (n + dk) * 8];
                acc = __builtin_amdgcn_mfma_f32_16x16x32_f16(a2[c], bfr, acc, 0, 0, 0);
            }
            if (n < 125) {
                uint2 p = pack4(lrelu(acc[0]), lrelu(acc[1]), lrelu(acc[2]), lrelu(acc[3]));
                *(uint2*)&V[(o16 >> 3) * 1008 + n * 8 + (o16 & 7)] = p;
            }
        }
        LDS_FENCE();

        // ---- pool1: act2 -> pooled U[2g][62] ----
        if (lane < 62) {
#pragma unroll
            for (int g = 0; g < 2; ++g) {
                h16x8 pa = *(const h16x8*)&V[g * 1008 + (2 * lane) * 8];
                h16x8 pb = *(const h16x8*)&V[g * 1008 + (2 * lane + 1) * 8];
                h16x8 mm;
#pragma unroll
                for (int e = 0; e < 8; ++e) mm[e] = pa[e] > pb[e] ? pa[e] : pb[e];
                *(h16x8*)&U[g * 1056 + lane * 8] = mm;
            }
        }
        LDS_FENCE();

        // ---- conv3 (32x32x16): pooled -> act3 V[4g][58] ----
#pragma unroll
        for (int t = 0; t < 2; ++t) {
            int n = t * 32 + n32;
            f32x16 acc = {0.f,0.f,0.f,0.f,0.f,0.f,0.f,0.f,0.f,0.f,0.f,0.f,0.f,0.f,0.f,0.f};
#pragma unroll
            for (int c = 0; c < 5; ++c) {
                h16x8 bfr = *(const h16x8*)&U[kg32 * 1056 + (n + c) * 8];
                acc = __builtin_amdgcn_mfma_f32_32x32x16_f16(a3[c], bfr, acc, 0, 0, 0);
            }
            if (n < 58) {
#pragma unroll
                for (int g = 0; g < 4; ++g) {
                    int r0 = 8 * g + 4 * kg32;
                    f32x4 bv = *(const f32x4*)&wsf[96 + r0];
                    uint2 p = pack4(lrelu(acc[4*g+0] + bv[0]), lrelu(acc[4*g+1] + bv[1]),
                                    lrelu(acc[4*g+2] + bv[2]), lrelu(acc[4*g+3] + bv[3]));
                    *(uint2*)&V[g * 552 + n * 8 + 4 * kg32] = p;
                }
            }
        }
        LDS_FENCE();

        // ---- conv4 (32x32x16): act3 -> act4 U[4g][54] ----
#pragma unroll
        for (int t = 0; t < 2; ++t) {
            int n = t * 32 + n32;
            f32x16 acc = {0.f,0.f,0.f,0.f,0.f,0.f,0.f,0.f,0.f,0.f,0.f,0.f,0.f,0.f,0.f,0.f};
#pragma unroll
            for (int c = 0; c < 10; ++c) {
                int k0 = c * 16 + kg32 * 8;
                int dk = k0 >> 5, g = (k0 >> 3) & 3;
                h16x8 bfr = *(const h16x8*)&V[g * 552 + (n + dk) * 8];
                acc = __builtin_amdgcn_mfma_f32_32x32x16_f16(a4[c], bfr, acc, 0, 0, 0);
            }
            if (n < 54) {
#pragma unroll
                for (int g = 0; g < 4; ++g) {
                    int r0 = 8 * g + 4 * kg32;
                    f32x4 bv = *(const f32x4*)&wsf[128 + r0];
                    uint2 p = pack4(lrelu(acc[4*g+0] + bv[0]), lrelu(acc[4*g+1] + bv[1]),
                                    lrelu(acc[4*g+2] + bv[2]), lrelu(acc[4*g+3] + bv[3]));
                    *(uint2*)&U[g * 448 + n * 8 + 4 * kg32] = p;
                }
            }
        }
        LDS_FENCE();

        // ---- pool2 + flatten: act4 -> flatb[slot], phys chunk = g*27 + pos ----
        if (lane < 27) {
#pragma unroll
            for (int g = 0; g < 4; ++g) {
                h16x8 pa = *(const h16x8*)&U[g * 448 + (2 * lane) * 8];
                h16x8 pb = *(const h16x8*)&U[g * 448 + (2 * lane + 1) * 8];
                h16x8 mm;
#pragma unroll
                for (int e = 0; e < 8; ++e) mm[e] = pa[e] > pb[e] ? pa[e] : pb[e];
                *(h16x8*)&flatb[slot][(g * 27 + lane) * 8] = mm;
            }
        }
    }
    __syncthreads();   // cross-wave: dense reads all 8 flatb slots

    // ---- dense (16x16x32): flatb[8][864] @ FD, wave w = m-tile ----
    int o0g = w * 16 + o16;
    f32x4 dacc = *(const f32x4*)&wsf[160 + o0g];  // bias in C
    for (int c = 0; c < 27; ++c) {
        h16x8 aw = *(const h16x8*)&FDg[((w * 27 + c) * 64 + lane) * 8];
        h16x8 bh = *(const h16x8*)&flatb[lane & 7][(kg16 * 27 + c) * 8];
        dacc = __builtin_amdgcn_mfma_f32_16x16x32_f16(aw, bh, dacc, 0, 0, 0);
    }
    f32x4 qov = *(const f32x4*)&wsf[224 + o0g];
    float part = 0.f;
#pragma unroll
    for (int q = 0; q < 4; ++q) part += lrelu(dacc[q]) * qov[q];
    red[tid] = part;
    __syncthreads();   // cross-wave: head reads all partials
    if (tid < 8) {
        float y = wsf[288];
#pragma unroll
        for (int g = 0; g < 16; ++g) y += red[(g >> 2) * 64 + (g & 3) * 16 + tid];
        if (f32flag) ((float*)out)[b0 + tid] = y;
        else         ((bf16*)out)[b0 + tid] = __float2bfloat16(y);
    }
}

extern "C" void kernel_launch(void* const* d_in, const int* in_sizes, int n_in,
                              void* d_out, int out_size, void* d_ws, size_t ws_size,
                              hipStream_t stream) {
    const void* x  = d_in[0];
    const void* w1 = d_in[1];
    const void* b1 = d_in[2];
    const void* w2 = d_in[3];
    const void* b2 = d_in[4];
    const void* w3 = d_in[5];
    const void* b3 = d_in[6];
    const void* w4 = d_in[7];
    const void* b4 = d_in[8];
    const void* wd = d_in[9];
    const void* bd = d_in[10];
    const void* wo = d_in[11];
    const void* bo = d_in[12];
    float* wsf = (float*)d_ws;

    int B = in_sizes[0] / 256;            // 32768
    prep<<<57, 256, 0, stream>>>((const unsigned short*)x,
                                 w1, w2, w3, w4, wd, wo,
                                 b1, b2, b3, b4, bd, bo, wsf);
    qcnn_main<<<B / 8, 256, 0, stream>>>(x, wsf, d_out);
}